// Round 3
// baseline (304.793 us; speedup 1.0000x reference)
//
#include <hip/hip_runtime.h>
#include <cstdint>
#include <cstddef>

#define S_LEN   2048
#define N_HEADS 8
#define N_BATCH 2
#define TOPK    409      // int(2048 * (1.0 - 0.8)) in python double arithmetic
#define HALF_WIN 32
#define NT      256
#define PT      8        // S_LEN / NT
#define KEY_P0  0x80000000u   // mono(+0.0f)
#define KEY_N0  0x7FFFFFFFu   // mono(-0.0f)  (total order: -0 < +0)

__device__ __forceinline__ unsigned mono(float f) {
  unsigned u = __float_as_uint(f);
  return (u & 0x80000000u) ? ~u : (u | 0x80000000u);
}

struct SelScratch {
  unsigned hist[256];
  unsigned sbuf[256];
  unsigned bk[2];
};

// Block-wide sum of c (256 threads).
__device__ __forceinline__ unsigned block_sum(unsigned c, SelScratch* s) {
  const int t = threadIdx.x;
  s->sbuf[t] = c;
  __syncthreads();
  #pragma unroll
  for (int d = 128; d > 0; d >>= 1) {
    if (t < d) s->sbuf[t] += s->sbuf[t + d];
    __syncthreads();
  }
  unsigned r = s->sbuf[0];
  __syncthreads();
  return r;
}

// Radix-select: find T = k-th largest key (2048 keys in LDS, total order on
// bits = XLA TOTALORDER on floats after mono()) and kk = how many keys equal
// to T must be taken (lowest-index-first) to reach exactly k.
// n0/n1 = counts of keys == KEY_P0 / KEY_N0 (the two +-0 tie groups, ~600
// each in k_final); they are histogrammed in bulk to avoid same-address LDS
// atomic serialization.
__device__ void radix_select(const unsigned* keys, int k, unsigned n0, unsigned n1,
                             SelScratch* s, unsigned* T_out, int* kk_out) {
  const int t = threadIdx.x;
  unsigned prefix = 0, done = 0;
  unsigned kk = (unsigned)k;
  #pragma unroll
  for (int shift = 24; shift >= 0; shift -= 8) {
    s->hist[t] = 0;
    __syncthreads();
    if (t == 0 && n0 != 0 && (KEY_P0 & done) == prefix)
      atomicAdd(&s->hist[(KEY_P0 >> shift) & 255u], n0);
    if (t == 1 && n1 != 0 && (KEY_N0 & done) == prefix)
      atomicAdd(&s->hist[(KEY_N0 >> shift) & 255u], n1);
    #pragma unroll
    for (int q = 0; q < PT; ++q) {
      unsigned kj = keys[t + NT * q];
      if (kj != KEY_P0 && kj != KEY_N0 && (kj & done) == prefix)
        atomicAdd(&s->hist[(kj >> shift) & 255u], 1u);
    }
    __syncthreads();
    s->sbuf[t] = s->hist[t];
    __syncthreads();
    // inclusive suffix sum (Hillis-Steele, 8 steps)
    for (int d = 1; d < 256; d <<= 1) {
      unsigned a = (t + d < 256) ? s->sbuf[t + d] : 0u;
      __syncthreads();
      s->sbuf[t] += a;
      __syncthreads();
    }
    unsigned suf_ge = s->sbuf[t];
    unsigned suf_gt = (t < 255) ? s->sbuf[t + 1] : 0u;
    if (suf_gt < kk && kk <= suf_ge) {   // exactly one t satisfies this
      s->bk[0] = (unsigned)t;
      s->bk[1] = kk - suf_gt;
    }
    __syncthreads();
    prefix |= s->bk[0] << shift;
    kk = s->bk[1];
    done |= 0xFFu << shift;
    __syncthreads();
  }
  *T_out = prefix;
  *kk_out = (int)kk;
}

// Exclusive scan over per-thread counts -> index-stable base rank for the
// contiguous chunk [t*PT, t*PT+PT).
__device__ __forceinline__ int stable_rank_base(int c, SelScratch* s) {
  const int t = threadIdx.x;
  s->sbuf[t] = (unsigned)c;
  __syncthreads();
  for (int d = 1; d < 256; d <<= 1) {
    unsigned a = (t >= d) ? s->sbuf[t - d] : 0u;
    __syncthreads();
    s->sbuf[t] += a;
    __syncthreads();
  }
  int base = (t == 0) ? 0 : (int)s->sbuf[t - 1];
  __syncthreads();
  return base;
}

// Kernel 1: one block per (b, i). Sequential-over-heads fp32 sum (matches
// reference mean rounding; /8 skipped - exact monotonic bit-order-preserving
// scaling), top-409 -> 2048-bit gmask row.
__global__ __launch_bounds__(NT) void k_gmask(const float* __restrict__ scores,
                                              unsigned* __restrict__ gwords) {
  __shared__ __align__(16) unsigned keys[S_LEN];
  __shared__ SelScratch scr;
  __shared__ __align__(4) unsigned char gb[NT];
  const int t = threadIdx.x;
  const int blk = blockIdx.x;          // b * S + i
  const int b = blk >> 11;
  const int i = blk & 2047;
  const size_t base = (((size_t)b * N_HEADS) * S_LEN + i) * S_LEN;

  unsigned c0 = 0, c1 = 0;
  #pragma unroll
  for (int s4 = 0; s4 < 2; ++s4) {
    const int j0 = (t + NT * s4) * 4;
    float4 a = *(const float4*)(scores + base + j0);
    #pragma unroll
    for (int h = 1; h < N_HEADS; ++h) {
      float4 x = *(const float4*)(scores + base + (size_t)h * S_LEN * S_LEN + j0);
      a.x += x.x; a.y += x.y; a.z += x.z; a.w += x.w;   // sequential h order
    }
    unsigned kqa[4] __attribute__((aligned(16)));
    kqa[0] = mono(a.x); kqa[1] = mono(a.y); kqa[2] = mono(a.z); kqa[3] = mono(a.w);
    #pragma unroll
    for (int q = 0; q < 4; ++q) {
      c0 += (kqa[q] == KEY_P0);
      c1 += (kqa[q] == KEY_N0);
    }
    *(uint4*)(&keys[j0]) = *(uint4*)kqa;
  }
  __syncthreads();

  unsigned ns = block_sum(c0 | (c1 << 16), &scr);
  unsigned T; int kk;
  radix_select(keys, TOPK, ns & 0xFFFFu, ns >> 16, &scr, &T, &kk);

  int c = 0;
  #pragma unroll
  for (int e = 0; e < PT; ++e) c += (keys[t * PT + e] == T);
  int r = stable_rank_base(c, &scr);

  unsigned byte = 0;
  #pragma unroll
  for (int e = 0; e < PT; ++e) {
    unsigned kj = keys[t * PT + e];
    bool sel;
    if (kj > T)       sel = true;
    else if (kj == T) { sel = (r < kk); ++r; }
    else              sel = false;
    byte |= (unsigned)sel << e;
  }
  gb[t] = (unsigned char)byte;
  __syncthreads();
  if (t < 64) gwords[(size_t)blk * 64 + t] = ((const unsigned*)gb)[t];
}

// Kernel 2: one block per (b, h, i) row. combined = local | gmask | random;
// masked value reproduced bit-exactly: combined ? score : copysign(0,score).
// Top-409 under total order with stable index ties -> write the 0/1 row.
__global__ __launch_bounds__(NT) void k_final(const float* __restrict__ scores,
                                              const float* __restrict__ randu,
                                              const unsigned* __restrict__ gwords,
                                              float* __restrict__ out) {
  __shared__ __align__(16) unsigned keys[S_LEN];
  __shared__ SelScratch scr;
  __shared__ unsigned gm[64];
  const int t = threadIdx.x;
  const int blk = blockIdx.x;          // (b*8 + h)*2048 + i
  const int i = blk & 2047;
  const int bh = blk >> 11;
  const int b = bh >> 3;
  const size_t base = (size_t)blk * S_LEN;
  const float thr = (float)(1.0 - 0.8); // 0x3E4CCCCD, same as JAX f32 demotion

  if (t < 64) gm[t] = gwords[((size_t)(b << 11) + i) * 64 + t];
  __syncthreads();

  unsigned c0 = 0, c1 = 0;
  #pragma unroll
  for (int s4 = 0; s4 < 2; ++s4) {
    const int j0 = (t + NT * s4) * 4;
    float4 sc = *(const float4*)(scores + base + j0);
    float4 ru = *(const float4*)(randu + base + j0);
    float scv[4] = {sc.x, sc.y, sc.z, sc.w};
    float ruv[4] = {ru.x, ru.y, ru.z, ru.w};
    unsigned kqa[4] __attribute__((aligned(16)));
    #pragma unroll
    for (int q = 0; q < 4; ++q) {
      const int j = j0 + q;
      bool loc = (j >= i - HALF_WIN) && (j < i + HALF_WIN);
      bool g   = (gm[j >> 5] >> (j & 31)) & 1u;
      bool rnd = ruv[q] < thr;
      unsigned u = __float_as_uint(scv[q]);
      unsigned key;
      if (loc || g || rnd) key = (u & 0x80000000u) ? ~u : (u | 0x80000000u);
      else                 key = (u >> 31) ? KEY_N0 : KEY_P0;  // mono(+-0)
      c0 += (key == KEY_P0);
      c1 += (key == KEY_N0);
      kqa[q] = key;
    }
    *(uint4*)(&keys[j0]) = *(uint4*)kqa;
  }
  __syncthreads();

  unsigned ns = block_sum(c0 | (c1 << 16), &scr);
  unsigned T; int kk;
  radix_select(keys, TOPK, ns & 0xFFFFu, ns >> 16, &scr, &T, &kk);

  int c = 0;
  #pragma unroll
  for (int e = 0; e < PT; ++e) c += (keys[t * PT + e] == T);
  int r = stable_rank_base(c, &scr);

  float vals[PT] __attribute__((aligned(16)));
  #pragma unroll
  for (int e = 0; e < PT; ++e) {
    unsigned kj = keys[t * PT + e];
    bool sel;
    if (kj > T)       sel = true;
    else if (kj == T) { sel = (r < kk); ++r; }
    else              sel = false;
    vals[e] = sel ? 1.0f : 0.0f;
  }
  float4* op = (float4*)(out + base + (size_t)t * PT);
  op[0] = *(float4*)&vals[0];
  op[1] = *(float4*)&vals[4];
}

extern "C" void kernel_launch(void* const* d_in, const int* in_sizes, int n_in,
                              void* d_out, int out_size, void* d_ws, size_t ws_size,
                              hipStream_t stream) {
  const float* scores = (const float*)d_in[0];
  const float* randu  = (const float*)d_in[1];
  float* out = (float*)d_out;
  unsigned* gwords = (unsigned*)d_ws;  // needs N_BATCH*S_LEN*256 B = 1 MiB
  k_gmask<<<N_BATCH * S_LEN, NT, 0, stream>>>(scores, gwords);
  k_final<<<N_BATCH * N_HEADS * S_LEN, NT, 0, stream>>>(scores, randu, gwords, out);
}

// Round 4
// 230.676 us; speedup vs baseline: 1.3213x; 1.3213x over previous
//
#include <hip/hip_runtime.h>
#include <cstdint>
#include <cstddef>

#define S_LEN   2048
#define N_HEADS 8
#define N_BATCH 2
#define TOPK    409      // int(2048 * (1.0 - 0.8)) in python double arithmetic
#define HALF_WIN 32
#define NT      256
#define PT      8        // S_LEN / NT
#define KEY_P0  0x80000000u   // mono(+0.0f)
#define KEY_N0  0x7FFFFFFFu   // mono(-0.0f)  (total order: -0 < +0)

__device__ __forceinline__ unsigned mono(float f) {
  unsigned u = __float_as_uint(f);
  return (u & 0x80000000u) ? ~u : (u | 0x80000000u);
}

__device__ __forceinline__ unsigned mbcnt64(unsigned long long m) {
  return __builtin_amdgcn_mbcnt_hi((unsigned)(m >> 32),
         __builtin_amdgcn_mbcnt_lo((unsigned)m, 0u));
}

// ------------------------- k_gmask (unchanged, at HBM roofline) -------------

struct SelScratch {
  unsigned hist[256];
  unsigned sbuf[256];
  unsigned bk[2];
};

__device__ __forceinline__ unsigned block_sum(unsigned c, SelScratch* s) {
  const int t = threadIdx.x;
  s->sbuf[t] = c;
  __syncthreads();
  #pragma unroll
  for (int d = 128; d > 0; d >>= 1) {
    if (t < d) s->sbuf[t] += s->sbuf[t + d];
    __syncthreads();
  }
  unsigned r = s->sbuf[0];
  __syncthreads();
  return r;
}

__device__ void radix_select(const unsigned* keys, int k, unsigned n0, unsigned n1,
                             SelScratch* s, unsigned* T_out, int* kk_out) {
  const int t = threadIdx.x;
  unsigned prefix = 0, done = 0;
  unsigned kk = (unsigned)k;
  #pragma unroll
  for (int shift = 24; shift >= 0; shift -= 8) {
    s->hist[t] = 0;
    __syncthreads();
    if (t == 0 && n0 != 0 && (KEY_P0 & done) == prefix)
      atomicAdd(&s->hist[(KEY_P0 >> shift) & 255u], n0);
    if (t == 1 && n1 != 0 && (KEY_N0 & done) == prefix)
      atomicAdd(&s->hist[(KEY_N0 >> shift) & 255u], n1);
    #pragma unroll
    for (int q = 0; q < PT; ++q) {
      unsigned kj = keys[t + NT * q];
      if (kj != KEY_P0 && kj != KEY_N0 && (kj & done) == prefix)
        atomicAdd(&s->hist[(kj >> shift) & 255u], 1u);
    }
    __syncthreads();
    s->sbuf[t] = s->hist[t];
    __syncthreads();
    for (int d = 1; d < 256; d <<= 1) {
      unsigned a = (t + d < 256) ? s->sbuf[t + d] : 0u;
      __syncthreads();
      s->sbuf[t] += a;
      __syncthreads();
    }
    unsigned suf_ge = s->sbuf[t];
    unsigned suf_gt = (t < 255) ? s->sbuf[t + 1] : 0u;
    if (suf_gt < kk && kk <= suf_ge) {
      s->bk[0] = (unsigned)t;
      s->bk[1] = kk - suf_gt;
    }
    __syncthreads();
    prefix |= s->bk[0] << shift;
    kk = s->bk[1];
    done |= 0xFFu << shift;
    __syncthreads();
  }
  *T_out = prefix;
  *kk_out = (int)kk;
}

__device__ __forceinline__ int stable_rank_base(int c, SelScratch* s) {
  const int t = threadIdx.x;
  s->sbuf[t] = (unsigned)c;
  __syncthreads();
  for (int d = 1; d < 256; d <<= 1) {
    unsigned a = (t >= d) ? s->sbuf[t - d] : 0u;
    __syncthreads();
    s->sbuf[t] += a;
    __syncthreads();
  }
  int base = (t == 0) ? 0 : (int)s->sbuf[t - 1];
  __syncthreads();
  return base;
}

__global__ __launch_bounds__(NT) void k_gmask(const float* __restrict__ scores,
                                              unsigned* __restrict__ gwords) {
  __shared__ __align__(16) unsigned keys[S_LEN];
  __shared__ SelScratch scr;
  __shared__ __align__(4) unsigned char gb[NT];
  const int t = threadIdx.x;
  const int blk = blockIdx.x;          // b * S + i
  const int b = blk >> 11;
  const int i = blk & 2047;
  const size_t base = (((size_t)b * N_HEADS) * S_LEN + i) * S_LEN;

  unsigned c0 = 0, c1 = 0;
  #pragma unroll
  for (int s4 = 0; s4 < 2; ++s4) {
    const int j0 = (t + NT * s4) * 4;
    float4 a = *(const float4*)(scores + base + j0);
    #pragma unroll
    for (int h = 1; h < N_HEADS; ++h) {
      float4 x = *(const float4*)(scores + base + (size_t)h * S_LEN * S_LEN + j0);
      a.x += x.x; a.y += x.y; a.z += x.z; a.w += x.w;   // sequential h order
    }
    unsigned kqa[4] __attribute__((aligned(16)));
    kqa[0] = mono(a.x); kqa[1] = mono(a.y); kqa[2] = mono(a.z); kqa[3] = mono(a.w);
    #pragma unroll
    for (int q = 0; q < 4; ++q) {
      c0 += (kqa[q] == KEY_P0);
      c1 += (kqa[q] == KEY_N0);
    }
    *(uint4*)(&keys[j0]) = *(uint4*)kqa;
  }
  __syncthreads();

  unsigned ns = block_sum(c0 | (c1 << 16), &scr);
  unsigned T; int kk;
  radix_select(keys, TOPK, ns & 0xFFFFu, ns >> 16, &scr, &T, &kk);

  int c = 0;
  #pragma unroll
  for (int e = 0; e < PT; ++e) c += (keys[t * PT + e] == T);
  int r = stable_rank_base(c, &scr);

  unsigned byte = 0;
  #pragma unroll
  for (int e = 0; e < PT; ++e) {
    unsigned kj = keys[t * PT + e];
    bool sel;
    if (kj > T)       sel = true;
    else if (kj == T) { sel = (r < kk); ++r; }
    else              sel = false;
    byte |= (unsigned)sel << e;
  }
  gb[t] = (unsigned char)byte;
  __syncthreads();
  if (t < 64) gwords[(size_t)blk * 64 + t] = ((const unsigned*)gb)[t];
}

// ------------------- k_final: one 64-lane wave per (b,h,i) row --------------
// Keys in registers (32/lane, static indexing). Histogram in a 1KB LDS array;
// all scans/reductions via shuffles/ballots -> only 2 cheap single-wave
// barriers per radix pass. Stable tie rank via ballot + mbcnt.

__global__ __launch_bounds__(64) void k_final(const float* __restrict__ scores,
                                              const float* __restrict__ randu,
                                              const unsigned* __restrict__ gwords,
                                              float* __restrict__ out) {
  __shared__ __align__(16) unsigned hist[256];
  __shared__ unsigned gm[64];
  const int l = threadIdx.x;           // lane 0..63
  const int blk = blockIdx.x;          // (b*8 + h)*2048 + i
  const int i = blk & 2047;
  const int b = blk >> 14;
  const size_t base = (size_t)blk * S_LEN;
  const float thr = (float)(1.0 - 0.8);   // 0x3E4CCCCD, JAX f32 demotion

  gm[l] = gwords[((size_t)(b << 11) + i) * 64 + l];
  __syncthreads();

  // Build 32 keys/lane: lane l owns j = 256*s + 4*l + e  (s=0..7, e=0..3).
  unsigned keys[32];
  unsigned c0 = 0, c1 = 0;
  #pragma unroll
  for (int s = 0; s < 8; ++s) {
    const int j0 = 256 * s + 4 * l;
    float4 sc = *(const float4*)(scores + base + j0);
    float4 ru = *(const float4*)(randu + base + j0);
    const unsigned gmw = gm[8 * s + (l >> 3)];
    const float scv[4] = {sc.x, sc.y, sc.z, sc.w};
    const float ruv[4] = {ru.x, ru.y, ru.z, ru.w};
    #pragma unroll
    for (int e = 0; e < 4; ++e) {
      const int j = j0 + e;
      bool loc = (j >= i - HALF_WIN) && (j < i + HALF_WIN);
      bool g   = (gmw >> (4 * (l & 7) + e)) & 1u;
      bool rnd = ruv[e] < thr;
      unsigned u = __float_as_uint(scv[e]);
      unsigned key;
      if (loc || g || rnd) key = (u & 0x80000000u) ? ~u : (u | 0x80000000u);
      else                 key = (u >> 31) ? KEY_N0 : KEY_P0;  // mono(+-0)
      c0 += (key == KEY_P0);
      c1 += (key == KEY_N0);
      keys[4 * s + e] = key;
    }
  }

  // Wave butterfly reduce of special counts (all lanes get totals).
  unsigned cs = c0 | (c1 << 16);
  #pragma unroll
  for (int d = 1; d < 64; d <<= 1) cs += __shfl_xor(cs, d);
  const unsigned n0 = cs & 0xFFFFu, n1 = cs >> 16;

  // 4-pass MSD radix select, barrier-light.
  unsigned prefix = 0, done = 0, kk = TOPK;
  #pragma unroll
  for (int shift = 24; shift >= 0; shift -= 8) {
    *(uint4*)&hist[l * 4] = make_uint4(0, 0, 0, 0);
    __syncthreads();
    if (l == 0 && n0 != 0 && (KEY_P0 & done) == prefix)
      atomicAdd(&hist[(KEY_P0 >> shift) & 255u], n0);
    if (l == 1 && n1 != 0 && (KEY_N0 & done) == prefix)
      atomicAdd(&hist[(KEY_N0 >> shift) & 255u], n1);
    #pragma unroll
    for (int q = 0; q < 32; ++q) {
      unsigned kj = keys[q];
      if (kj != KEY_P0 && kj != KEY_N0 && (kj & done) == prefix)
        atomicAdd(&hist[(kj >> shift) & 255u], 1u);
    }
    __syncthreads();
    // Suffix-sum over 256 bins: 4 bins/lane local suffix + wave suffix scan.
    uint4 hv = *(const uint4*)&hist[l * 4];
    unsigned s3 = hv.w;
    unsigned s2 = hv.z + s3;
    unsigned s1 = hv.y + s2;
    unsigned s0 = hv.x + s1;
    unsigned inc = s0;                       // inclusive over lanes >= l
    #pragma unroll
    for (int d = 1; d < 64; d <<= 1) {
      unsigned o = __shfl_down(inc, d);
      inc += (l + d < 64) ? o : 0u;
    }
    const unsigned tail = inc - s0;          // sum over lanes > l
    // bin 4l+q: suf_ge = s_q + tail ; suf_gt = (q<3 ? s_{q+1} : 0) + tail
    const unsigned ge[4] = {s0 + tail, s1 + tail, s2 + tail, s3 + tail};
    const unsigned gt[4] = {s1 + tail, s2 + tail, s3 + tail, tail};
    unsigned packed = 0;
    bool found = false;
    #pragma unroll
    for (int q = 0; q < 4; ++q) {
      if (gt[q] < kk && kk <= ge[q]) {       // exactly one (lane,q) in wave
        packed = ((unsigned)(4 * l + q) << 12) | (kk - gt[q]);
        found = true;
      }
    }
    unsigned long long bal = __ballot(found);
    int srcl = __ffsll((long long)bal) - 1;
    packed = __shfl(packed, srcl);
    prefix |= (packed >> 12) << shift;
    kk = packed & 0xFFFu;
    done |= 0xFFu << shift;
  }
  const unsigned T = prefix;

  // Stable-rank selection + coalesced write.
  unsigned S_before = 0;                     // ties in j-blocks s' < s
  #pragma unroll
  for (int s = 0; s < 8; ++s) {
    unsigned long long bal[4];
    unsigned mb[4], own[4];
    #pragma unroll
    for (int e = 0; e < 4; ++e) {
      bal[e] = __ballot(keys[4 * s + e] == T);
      mb[e]  = mbcnt64(bal[e]);
      own[e] = (unsigned)((bal[e] >> l) & 1ull);
    }
    const unsigned cross = S_before + mb[0] + mb[1] + mb[2] + mb[3];
    float v[4] __attribute__((aligned(16)));
    unsigned run = 0;
    #pragma unroll
    for (int e = 0; e < 4; ++e) {
      unsigned kj = keys[4 * s + e];
      bool sel = (kj > T) || (kj == T && (cross + run) < kk);
      run += own[e];
      v[e] = sel ? 1.0f : 0.0f;
    }
    *(float4*)(out + base + 256 * s + 4 * l) = *(const float4*)v;
    S_before += (unsigned)(__popcll(bal[0]) + __popcll(bal[1]) +
                           __popcll(bal[2]) + __popcll(bal[3]));
  }
}

extern "C" void kernel_launch(void* const* d_in, const int* in_sizes, int n_in,
                              void* d_out, int out_size, void* d_ws, size_t ws_size,
                              hipStream_t stream) {
  const float* scores = (const float*)d_in[0];
  const float* randu  = (const float*)d_in[1];
  float* out = (float*)d_out;
  unsigned* gwords = (unsigned*)d_ws;  // needs N_BATCH*S_LEN*256 B = 1 MiB
  k_gmask<<<N_BATCH * S_LEN, NT, 0, stream>>>(scores, gwords);
  k_final<<<N_BATCH * N_HEADS * S_LEN, 64, 0, stream>>>(scores, randu, gwords, out);
}

// Round 5
// 227.243 us; speedup vs baseline: 1.3413x; 1.0151x over previous
//
#include <hip/hip_runtime.h>
#include <cstdint>
#include <cstddef>

#define S_LEN   2048
#define N_HEADS 8
#define N_BATCH 2
#define TOPK    409      // int(2048 * (1.0 - 0.8)) in python double arithmetic
#define HALF_WIN 32
#define NT      256
#define PT      8        // S_LEN / NT
#define KEY_P0  0x80000000u   // mono(+0.0f)
#define KEY_N0  0x7FFFFFFFu   // mono(-0.0f)  (total order: -0 < +0)

__device__ __forceinline__ unsigned mono(float f) {
  unsigned u = __float_as_uint(f);
  return (u & 0x80000000u) ? ~u : (u | 0x80000000u);
}

__device__ __forceinline__ unsigned mbcnt64(unsigned long long m) {
  return __builtin_amdgcn_mbcnt_hi((unsigned)(m >> 32),
         __builtin_amdgcn_mbcnt_lo((unsigned)m, 0u));
}

// ------------------------- k_gmask (unchanged, at HBM roofline) -------------

struct SelScratch {
  unsigned hist[256];
  unsigned sbuf[256];
  unsigned bk[2];
};

__device__ __forceinline__ unsigned block_sum(unsigned c, SelScratch* s) {
  const int t = threadIdx.x;
  s->sbuf[t] = c;
  __syncthreads();
  #pragma unroll
  for (int d = 128; d > 0; d >>= 1) {
    if (t < d) s->sbuf[t] += s->sbuf[t + d];
    __syncthreads();
  }
  unsigned r = s->sbuf[0];
  __syncthreads();
  return r;
}

__device__ void radix_select(const unsigned* keys, int k, unsigned n0, unsigned n1,
                             SelScratch* s, unsigned* T_out, int* kk_out) {
  const int t = threadIdx.x;
  unsigned prefix = 0, done = 0;
  unsigned kk = (unsigned)k;
  #pragma unroll
  for (int shift = 24; shift >= 0; shift -= 8) {
    s->hist[t] = 0;
    __syncthreads();
    if (t == 0 && n0 != 0 && (KEY_P0 & done) == prefix)
      atomicAdd(&s->hist[(KEY_P0 >> shift) & 255u], n0);
    if (t == 1 && n1 != 0 && (KEY_N0 & done) == prefix)
      atomicAdd(&s->hist[(KEY_N0 >> shift) & 255u], n1);
    #pragma unroll
    for (int q = 0; q < PT; ++q) {
      unsigned kj = keys[t + NT * q];
      if (kj != KEY_P0 && kj != KEY_N0 && (kj & done) == prefix)
        atomicAdd(&s->hist[(kj >> shift) & 255u], 1u);
    }
    __syncthreads();
    s->sbuf[t] = s->hist[t];
    __syncthreads();
    for (int d = 1; d < 256; d <<= 1) {
      unsigned a = (t + d < 256) ? s->sbuf[t + d] : 0u;
      __syncthreads();
      s->sbuf[t] += a;
      __syncthreads();
    }
    unsigned suf_ge = s->sbuf[t];
    unsigned suf_gt = (t < 255) ? s->sbuf[t + 1] : 0u;
    if (suf_gt < kk && kk <= suf_ge) {
      s->bk[0] = (unsigned)t;
      s->bk[1] = kk - suf_gt;
    }
    __syncthreads();
    prefix |= s->bk[0] << shift;
    kk = s->bk[1];
    done |= 0xFFu << shift;
    __syncthreads();
  }
  *T_out = prefix;
  *kk_out = (int)kk;
}

__device__ __forceinline__ int stable_rank_base(int c, SelScratch* s) {
  const int t = threadIdx.x;
  s->sbuf[t] = (unsigned)c;
  __syncthreads();
  for (int d = 1; d < 256; d <<= 1) {
    unsigned a = (t >= d) ? s->sbuf[t - d] : 0u;
    __syncthreads();
    s->sbuf[t] += a;
    __syncthreads();
  }
  int base = (t == 0) ? 0 : (int)s->sbuf[t - 1];
  __syncthreads();
  return base;
}

__global__ __launch_bounds__(NT) void k_gmask(const float* __restrict__ scores,
                                              unsigned* __restrict__ gwords) {
  __shared__ __align__(16) unsigned keys[S_LEN];
  __shared__ SelScratch scr;
  __shared__ __align__(4) unsigned char gb[NT];
  const int t = threadIdx.x;
  const int blk = blockIdx.x;          // b * S + i
  const int b = blk >> 11;
  const int i = blk & 2047;
  const size_t base = (((size_t)b * N_HEADS) * S_LEN + i) * S_LEN;

  unsigned c0 = 0, c1 = 0;
  #pragma unroll
  for (int s4 = 0; s4 < 2; ++s4) {
    const int j0 = (t + NT * s4) * 4;
    float4 a = *(const float4*)(scores + base + j0);
    #pragma unroll
    for (int h = 1; h < N_HEADS; ++h) {
      float4 x = *(const float4*)(scores + base + (size_t)h * S_LEN * S_LEN + j0);
      a.x += x.x; a.y += x.y; a.z += x.z; a.w += x.w;   // sequential h order
    }
    unsigned kqa[4] __attribute__((aligned(16)));
    kqa[0] = mono(a.x); kqa[1] = mono(a.y); kqa[2] = mono(a.z); kqa[3] = mono(a.w);
    #pragma unroll
    for (int q = 0; q < 4; ++q) {
      c0 += (kqa[q] == KEY_P0);
      c1 += (kqa[q] == KEY_N0);
    }
    *(uint4*)(&keys[j0]) = *(uint4*)kqa;
  }
  __syncthreads();

  unsigned ns = block_sum(c0 | (c1 << 16), &scr);
  unsigned T; int kk;
  radix_select(keys, TOPK, ns & 0xFFFFu, ns >> 16, &scr, &T, &kk);

  int c = 0;
  #pragma unroll
  for (int e = 0; e < PT; ++e) c += (keys[t * PT + e] == T);
  int r = stable_rank_base(c, &scr);

  unsigned byte = 0;
  #pragma unroll
  for (int e = 0; e < PT; ++e) {
    unsigned kj = keys[t * PT + e];
    bool sel;
    if (kj > T)       sel = true;
    else if (kj == T) { sel = (r < kk); ++r; }
    else              sel = false;
    byte |= (unsigned)sel << e;
  }
  gb[t] = (unsigned char)byte;
  __syncthreads();
  if (t < 64) gwords[(size_t)blk * 64 + t] = ((const unsigned*)gb)[t];
}

// ------------------- k_final: one 64-lane wave per (b,h,i) row --------------
// Keys in registers (32/lane, static indexing). 256-bin LDS histogram; scans
// via shuffles. NEW: early exit from the radix loop when the surviving bucket
// is (A) exactly one +-0 tie group (T = that special key; ~50% of rows after
// pass 1, since bucket 0x80 holds only +0 for N(0,1) data) or (B) a single
// key (register scan + OR-reduce broadcast). Both exits are mathematically
// equivalent to running all 4 passes.

__global__ __launch_bounds__(64) void k_final(const float* __restrict__ scores,
                                              const float* __restrict__ randu,
                                              const unsigned* __restrict__ gwords,
                                              float* __restrict__ out) {
  __shared__ __align__(16) unsigned hist[256];
  __shared__ unsigned gm[64];
  const int l = threadIdx.x;           // lane 0..63
  const int blk = blockIdx.x;          // (b*8 + h)*2048 + i
  const int i = blk & 2047;
  const int b = blk >> 14;
  const size_t base = (size_t)blk * S_LEN;
  const float thr = (float)(1.0 - 0.8);   // 0x3E4CCCCD, JAX f32 demotion

  gm[l] = gwords[((size_t)(b << 11) + i) * 64 + l];
  __syncthreads();

  // Build 32 keys/lane: lane l owns j = 256*s + 4*l + e  (s=0..7, e=0..3).
  unsigned keys[32];
  unsigned c0 = 0, c1 = 0;
  #pragma unroll
  for (int s = 0; s < 8; ++s) {
    const int j0 = 256 * s + 4 * l;
    float4 sc = *(const float4*)(scores + base + j0);
    float4 ru = *(const float4*)(randu + base + j0);
    const unsigned gmw = gm[8 * s + (l >> 3)];
    const float scv[4] = {sc.x, sc.y, sc.z, sc.w};
    const float ruv[4] = {ru.x, ru.y, ru.z, ru.w};
    #pragma unroll
    for (int e = 0; e < 4; ++e) {
      const int j = j0 + e;
      bool loc = (j >= i - HALF_WIN) && (j < i + HALF_WIN);
      bool g   = (gmw >> (4 * (l & 7) + e)) & 1u;
      bool rnd = ruv[e] < thr;
      unsigned u = __float_as_uint(scv[e]);
      unsigned key;
      if (loc || g || rnd) key = (u & 0x80000000u) ? ~u : (u | 0x80000000u);
      else                 key = (u >> 31) ? KEY_N0 : KEY_P0;  // mono(+-0)
      c0 += (key == KEY_P0);
      c1 += (key == KEY_N0);
      keys[4 * s + e] = key;
    }
  }

  // Wave butterfly reduce of special counts (all lanes get totals).
  unsigned cs = c0 | (c1 << 16);
  #pragma unroll
  for (int d = 1; d < 64; d <<= 1) cs += __shfl_xor(cs, d);
  const unsigned n0 = cs & 0xFFFFu, n1 = cs >> 16;

  // MSD radix select with early exits.
  unsigned prefix = 0, done = 0, kk = TOPK;
  unsigned T = 0;
  bool resolved = false;
  #pragma unroll
  for (int pass = 0; pass < 4; ++pass) {
    const int shift = 24 - 8 * pass;
    *(uint4*)&hist[l * 4] = make_uint4(0, 0, 0, 0);
    __syncthreads();
    if (l == 0 && n0 != 0 && (KEY_P0 & done) == prefix)
      atomicAdd(&hist[(KEY_P0 >> shift) & 255u], n0);
    if (l == 1 && n1 != 0 && (KEY_N0 & done) == prefix)
      atomicAdd(&hist[(KEY_N0 >> shift) & 255u], n1);
    #pragma unroll
    for (int q = 0; q < 32; ++q) {
      unsigned kj = keys[q];
      if (kj != KEY_P0 && kj != KEY_N0 && (kj & done) == prefix)
        atomicAdd(&hist[(kj >> shift) & 255u], 1u);
    }
    __syncthreads();
    // Suffix-sum over 256 bins: 4 bins/lane local suffix + wave suffix scan.
    uint4 hv = *(const uint4*)&hist[l * 4];
    unsigned s3 = hv.w;
    unsigned s2 = hv.z + s3;
    unsigned s1 = hv.y + s2;
    unsigned s0 = hv.x + s1;
    unsigned inc = s0;                       // inclusive over lanes >= l
    #pragma unroll
    for (int d = 1; d < 64; d <<= 1) {
      unsigned o = __shfl_down(inc, d);
      inc += (l + d < 64) ? o : 0u;
    }
    const unsigned tail = inc - s0;          // sum over lanes > l
    const unsigned ge[4] = {s0 + tail, s1 + tail, s2 + tail, s3 + tail};
    const unsigned gt[4] = {s1 + tail, s2 + tail, s3 + tail, tail};
    unsigned packed = 0;
    bool found = false;
    #pragma unroll
    for (int q = 0; q < 4; ++q) {
      if (gt[q] < kk && kk <= ge[q]) {       // exactly one (lane,q) in wave
        // digit(8) | bucket_count(12) | kk_residual(12); counts <= 2048 fit.
        packed = ((unsigned)(4 * l + q) << 24) | ((ge[q] - gt[q]) << 12) | (kk - gt[q]);
        found = true;
      }
    }
    unsigned long long bal = __ballot(found);
    int srcl = __ffsll((long long)bal) - 1;
    packed = __shfl(packed, srcl);
    const unsigned cnt = (packed >> 12) & 0xFFFu;
    kk = packed & 0xFFFu;
    prefix |= (packed >> 24) << shift;
    done |= 0xFFu << shift;

    // Exit A: bucket is exactly one +-0 tie group -> T is that special key.
    const unsigned m0 = ((KEY_P0 & done) == prefix) ? n0 : 0u;
    const unsigned m1 = ((KEY_N0 & done) == prefix) ? n1 : 0u;
    if (cnt == m0 + m1 && (m0 == 0u || m1 == 0u)) {
      T = m0 ? KEY_P0 : KEY_N0;
      resolved = true;
      break;
    }
    // Exit B: single surviving key -> find it in registers, broadcast.
    if (cnt == 1u) {
      unsigned cand = 0;
      #pragma unroll
      for (int q = 0; q < 32; ++q) {
        unsigned kj = keys[q];
        if (kj != KEY_P0 && kj != KEY_N0 && (kj & done) == prefix) cand = kj;
      }
      #pragma unroll
      for (int d = 1; d < 64; d <<= 1) cand |= __shfl_xor(cand, d);
      T = cand;                              // kk == 1 here by construction
      resolved = true;
      break;
    }
  }
  if (!resolved) T = prefix;

  // Stable-rank selection + coalesced write.
  unsigned S_before = 0;                     // ties in j-blocks s' < s
  #pragma unroll
  for (int s = 0; s < 8; ++s) {
    unsigned long long bal[4];
    unsigned mb[4], own[4];
    #pragma unroll
    for (int e = 0; e < 4; ++e) {
      bal[e] = __ballot(keys[4 * s + e] == T);
      mb[e]  = mbcnt64(bal[e]);
      own[e] = (unsigned)((bal[e] >> l) & 1ull);
    }
    const unsigned cross = S_before + mb[0] + mb[1] + mb[2] + mb[3];
    float v[4] __attribute__((aligned(16)));
    unsigned run = 0;
    #pragma unroll
    for (int e = 0; e < 4; ++e) {
      unsigned kj = keys[4 * s + e];
      bool sel = (kj > T) || (kj == T && (cross + run) < kk);
      run += own[e];
      v[e] = sel ? 1.0f : 0.0f;
    }
    *(float4*)(out + base + 256 * s + 4 * l) = *(const float4*)v;
    S_before += (unsigned)(__popcll(bal[0]) + __popcll(bal[1]) +
                           __popcll(bal[2]) + __popcll(bal[3]));
  }
}

extern "C" void kernel_launch(void* const* d_in, const int* in_sizes, int n_in,
                              void* d_out, int out_size, void* d_ws, size_t ws_size,
                              hipStream_t stream) {
  const float* scores = (const float*)d_in[0];
  const float* randu  = (const float*)d_in[1];
  float* out = (float*)d_out;
  unsigned* gwords = (unsigned*)d_ws;  // needs N_BATCH*S_LEN*256 B = 1 MiB
  k_gmask<<<N_BATCH * S_LEN, NT, 0, stream>>>(scores, gwords);
  k_final<<<N_BATCH * N_HEADS * S_LEN, 64, 0, stream>>>(scores, randu, gwords, out);
}